// Round 6
// baseline (3037.684 us; speedup 1.0000x reference)
//
#include <hip/hip_runtime.h>
#include <hip/hip_bf16.h>

// B=4, N=8192, S=2048, C=128, c_in=131, c_out=256, K=20 (fixed by setup_inputs).
//
// Algebra: h = (knn_feat-center)@W1 + center@W2 = P[knn_idx] + Q.
// BN(gamma>0) and ReLU monotone => max_k commutes.
//
// ws layout (needs ~6.3 MB): see kernel_launch.

#define NPTS   8192
#define NSAMP  2048
#define KNN    20

// ---------- DPP reduction helpers (GCN/CDNA row ops, wave64) ----------
// full-wave sequence: xor1(qp 0xB1), xor2(qp 0x4E), ror4(0x124), ror8(0x128)
//   -> every lane has its row-of-16 reduced; bcast15(0x142,rm 0xa),
//   bcast31(0x143,rm 0xc) -> lanes 48-63 hold the wave result (readlane 63).
template<int CTRL, int RM>
__device__ __forceinline__ float dpp_fmax(float x) {
  int t = __builtin_amdgcn_update_dpp(__float_as_int(x), __float_as_int(x),
                                      CTRL, RM, 0xf, false);
  return fmaxf(x, __int_as_float(t));
}

template<int CTRL, int RM>
__device__ __forceinline__ unsigned long long dpp_kmax(unsigned long long k) {
  unsigned lo = (unsigned)k, hi = (unsigned)(k >> 32);
  unsigned lo2 = (unsigned)__builtin_amdgcn_update_dpp((int)lo, (int)lo, CTRL, RM, 0xf, false);
  unsigned hi2 = (unsigned)__builtin_amdgcn_update_dpp((int)hi, (int)hi, CTRL, RM, 0xf, false);
  unsigned long long o = ((unsigned long long)hi2 << 32) | lo2;
  return o > k ? o : k;
}

template<int CTRL, int RM>
__device__ __forceinline__ unsigned long long dpp_kmin(unsigned long long k) {
  unsigned lo = (unsigned)k, hi = (unsigned)(k >> 32);
  unsigned lo2 = (unsigned)__builtin_amdgcn_update_dpp((int)lo, (int)lo, CTRL, RM, 0xf, false);
  unsigned hi2 = (unsigned)__builtin_amdgcn_update_dpp((int)hi, (int)hi, CTRL, RM, 0xf, false);
  unsigned long long o = ((unsigned long long)hi2 << 32) | lo2;
  return o < k ? o : k;
}

// FPS v5: 4 waves (1/SIMD), 32 pts/thread in registers. Reduction overhead is
// paid once per SIMD; cross-wave fold is 4 keys (2 quad_perm DPP stages).
// Exact fp: d = ((dx*dx+dy*dy)+dz*dz) in _rn ops; argmax = first max.
__global__ __launch_bounds__(256, 1) void fps_kernel(
    const float* __restrict__ xyz, const int* __restrict__ farthest0,
    int* __restrict__ sample_int, float* __restrict__ out) {
  __shared__ float s_x[NPTS], s_y[NPTS], s_z[NPTS];   // 96 KiB
  __shared__ unsigned long long skey[2][4];
  const int b = blockIdx.x, tid = threadIdx.x;
  const int lane = tid & 63, wid = tid >> 6;
  const float* xb = xyz + (size_t)b * NPTS * 3;

  for (int p = tid; p < NPTS; p += 256) {
    s_x[p] = xb[3*p]; s_y[p] = xb[3*p+1]; s_z[p] = xb[3*p+2];
  }
  __syncthreads();

  float px[32], py[32], pz[32], dist[32];
#pragma unroll
  for (int j = 0; j < 32; ++j) {
    int p = tid*32 + j;                      // contiguous ownership
    px[j] = s_x[p]; py[j] = s_y[p]; pz[j] = s_z[p];
    dist[j] = 1e10f;                         // reference init 10000000000.0
  }
  int cur = farthest0[b];
  float* outxyz = out + (size_t)b * NSAMP * 3;
  float* outidx = out + 24576 + 2097152 + (size_t)b * NSAMP;

  for (int it = 0; it < NSAMP; ++it) {
    float cx = s_x[cur], cy = s_y[cur], cz = s_z[cur];   // uniform -> LDS broadcast
    if (tid == 0) {                          // scan emits carry (index before update)
      sample_int[(b << 11) + it] = cur;
      outidx[it] = (float)cur;
      outxyz[3*it] = cx; outxyz[3*it+1] = cy; outxyz[3*it+2] = cz;
    }
    if (it == NSAMP - 1) break;              // last winner never emitted

    // strict IEEE update, no FMA contraction
#pragma unroll
    for (int j = 0; j < 32; ++j) {
      float dx = __fsub_rn(px[j], cx);
      float dy = __fsub_rn(py[j], cy);
      float dz = __fsub_rn(pz[j], cz);
      float d  = __fadd_rn(__fadd_rn(__fmul_rn(dx,dx), __fmul_rn(dy,dy)), __fmul_rn(dz,dz));
      dist[j] = fminf(dist[j], d);
    }
    // per-thread max, explicit tree (constant indices only)
    float red[16];
#pragma unroll
    for (int j = 0; j < 16; ++j) red[j] = fmaxf(dist[2*j], dist[2*j+1]);
#pragma unroll
    for (int s = 8; s >= 1; s >>= 1)
#pragma unroll
      for (int j = 0; j < 8; ++j)
        if (j < s) red[j] = fmaxf(red[j], red[j+s]);
    float lm = red[0];

    // wave max via DPP, result in lane 63
    float m = lm;
    m = dpp_fmax<0xB1, 0xf>(m);
    m = dpp_fmax<0x4E, 0xf>(m);
    m = dpp_fmax<0x124, 0xf>(m);
    m = dpp_fmax<0x128, 0xf>(m);
    m = dpp_fmax<0x142, 0xa>(m);
    m = dpp_fmax<0x143, 0xc>(m);
    float M = __int_as_float(__builtin_amdgcn_readlane(__float_as_int(m), 63));

    // index recovery: lowest matching lane = smallest global index (contiguous)
    unsigned long long ball = __ballot(lm == M);
    int wl = __ffsll(ball) - 1;
    if (lane == wl) {
      int jb = 31;
#pragma unroll
      for (int jj = 31; jj >= 0; --jj)
        if (dist[jj] == M) jb = jj;          // smallest slot wins
      unsigned g = (unsigned)(tid*32 + jb);
      skey[it & 1][wid] = ((unsigned long long)__float_as_uint(M) << 32)
                          | (unsigned)(~g);  // max value, tie -> smallest index
    }
    __syncthreads();                         // the ONLY barrier per iteration
    // cross-wave fold: each quad folds the same 4 keys via 2 DPP stages
    unsigned long long k = skey[it & 1][lane & 3];
    k = dpp_kmax<0xB1, 0xf>(k);
    k = dpp_kmax<0x4E, 0xf>(k);
    cur = (int)(~(unsigned)k);
  }
}

// kNN v3: 1 wave/query, two chunks of 4096 pts (64 regs/lane), masked argmin
// extraction with DPP u64 wave-min, exact merge of the two sorted top-20 lists.
__global__ __launch_bounds__(256) void knn_kernel(
    const float* __restrict__ xyz, const int* __restrict__ sample_int,
    int* __restrict__ knn_out) {
  __shared__ unsigned long long lists[4][2][KNN];
  const int tid  = threadIdx.x;
  const int lane = tid & 63, w = tid >> 6;
  const int qq   = blockIdx.x * 4 + w;
  const int b    = qq >> 11;
  const float* xb = xyz + (size_t)b * NPTS * 3;
  const int sidx = sample_int[qq];
  const float sx = xb[3*sidx], sy = xb[3*sidx+1], sz = xb[3*sidx+2];
  const float sqs = __fadd_rn(__fadd_rn(__fmul_rn(sx,sx), __fmul_rn(sy,sy)), __fmul_rn(sz,sz));

  for (int ch = 0; ch < 2; ++ch) {
    const int pbase = ch * 4096;
    float d[64];
#pragma unroll
    for (int i = 0; i < 64; ++i) {
      int p = pbase + i*64 + lane;
      float x = xb[3*p], y = xb[3*p+1], z = xb[3*p+2];
      float dot = __fadd_rn(__fadd_rn(__fmul_rn(sx,x), __fmul_rn(sy,y)), __fmul_rn(sz,z));
      float sqx = __fadd_rn(__fadd_rn(__fmul_rn(x,x), __fmul_rn(y,y)), __fmul_rn(z,z));
      d[i] = __fadd_rn(__fsub_rn(sqs, __fmul_rn(2.0f, dot)), sqx);  // (||s||^2-2dot)+||x||^2
    }
    unsigned long long msk = 0ull;
    for (int kk = 0; kk < KNN; ++kk) {
      // per-lane masked argmin (compile-time indices only)
      float bv = 1e30f; int bs = 0;
#pragma unroll
      for (int i = 0; i < 64; ++i) {
        float dc = (msk & (1ull << i)) ? 1e30f : d[i];
        if (dc < bv) { bv = dc; bs = i; }   // strict <: smallest slot on ties
      }
      unsigned gi = (unsigned)(pbase + bs*64 + lane);
      unsigned long long key = ((unsigned long long)__float_as_uint(bv) << 32) | gi;
      key = dpp_kmin<0xB1, 0xf>(key);
      key = dpp_kmin<0x4E, 0xf>(key);
      key = dpp_kmin<0x124, 0xf>(key);
      key = dpp_kmin<0x128, 0xf>(key);
      key = dpp_kmin<0x142, 0xa>(key);
      key = dpp_kmin<0x143, 0xc>(key);
      unsigned glo = (unsigned)__builtin_amdgcn_readlane((int)(unsigned)key, 63);
      unsigned ghi = (unsigned)__builtin_amdgcn_readlane((int)(unsigned)(key >> 32), 63);
      if (lane == (int)(glo & 63u)) msk |= 1ull << ((glo - pbase) >> 6);
      if (lane == 0) lists[w][ch][kk] = ((unsigned long long)ghi << 32) | glo;
    }
  }
  // merge the two ascending 20-lists by exact rank (keys distinct: idx unique)
  unsigned long long mykey = ~0ull; int rank = 64;
  if (lane < 40) {
    int li = lane >= 20 ? 1 : 0;
    int e  = li ? lane - 20 : lane;
    mykey = lists[w][li][e];
    int cnt = e;
    const unsigned long long* oth = &lists[w][li ^ 1][0];
#pragma unroll
    for (int j = 0; j < KNN; ++j) cnt += (oth[j] < mykey) ? 1 : 0;
    rank = cnt;
  }
  if (rank < KNN) knn_out[(size_t)qq * KNN + rank] = (int)(mykey & 0xFFFFFFFFull);
}

__global__ void wdiff_kernel(const float* __restrict__ W, float* __restrict__ Wd) {
  int i = blockIdx.x * 256 + threadIdx.x;      // 131 blocks * 256 = 33536 exactly
  Wd[i] = W[131*256 + i] - W[i];
}

// OUT[row, c] = sum_{k<131} A(row)[k] * W[k*256+c]
template<bool BF16OUT>
__global__ __launch_bounds__(128) void matmul131_kernel(
    const float* __restrict__ featb, const float* __restrict__ xyzb,
    const int* __restrict__ gidx,
    const float* __restrict__ W, void* __restrict__ outp) {
  __shared__ float tile[32][132];
  const int tid = threadIdx.x;
  const int r0  = blockIdx.x << 5;
  for (int i = tid; i < 32*131; i += 128) {
    int r = i / 131;
    int k = i - r*131;
    int row = r0 + r;
    int src;
    if (gidx) { int bb = row >> 11; src = (bb << 13) + gidx[row]; }
    else      { src = row; }
    float v = (k < 128) ? featb[(size_t)src*128 + k]
                        : xyzb[(size_t)src*3 + (k-128)];
    tile[r][k] = v;
  }
  __syncthreads();
  float acc0[32], acc1[32];
#pragma unroll
  for (int r = 0; r < 32; ++r) { acc0[r] = 0.f; acc1[r] = 0.f; }
  const int c0 = tid, c1 = tid + 128;
  for (int k = 0; k < 128; k += 4) {
    float w00 = W[(k+0)*256+c0], w01 = W[(k+1)*256+c0], w02 = W[(k+2)*256+c0], w03 = W[(k+3)*256+c0];
    float w10 = W[(k+0)*256+c1], w11 = W[(k+1)*256+c1], w12 = W[(k+2)*256+c1], w13 = W[(k+3)*256+c1];
#pragma unroll
    for (int r = 0; r < 32; ++r) {
      float4 a = *(const float4*)&tile[r][k];
      acc0[r] = fmaf(a.x, w00, acc0[r]); acc0[r] = fmaf(a.y, w01, acc0[r]);
      acc0[r] = fmaf(a.z, w02, acc0[r]); acc0[r] = fmaf(a.w, w03, acc0[r]);
      acc1[r] = fmaf(a.x, w10, acc1[r]); acc1[r] = fmaf(a.y, w11, acc1[r]);
      acc1[r] = fmaf(a.z, w12, acc1[r]); acc1[r] = fmaf(a.w, w13, acc1[r]);
    }
  }
#pragma unroll
  for (int kk = 128; kk < 131; ++kk) {
    float w0 = W[kk*256+c0], w1 = W[kk*256+c1];
#pragma unroll
    for (int r = 0; r < 32; ++r) {
      float a = tile[r][kk];
      acc0[r] = fmaf(a, w0, acc0[r]);
      acc1[r] = fmaf(a, w1, acc1[r]);
    }
  }
#pragma unroll
  for (int r = 0; r < 32; ++r) {
    if (BF16OUT) {
      __hip_bfloat16* o = (__hip_bfloat16*)outp;
      o[(size_t)(r0+r)*256 + c0] = __float2bfloat16(acc0[r]);
      o[(size_t)(r0+r)*256 + c1] = __float2bfloat16(acc1[r]);
    } else {
      float* o = (float*)outp;
      o[(size_t)(r0+r)*256 + c0] = acc0[r];
      o[(size_t)(r0+r)*256 + c1] = acc1[r];
    }
  }
}

// One batch per launch. Qb == outFeat: each (qq,c) element is read (qc) exactly
// once by the thread that later overwrites it with maxh.
__global__ __launch_bounds__(256) void stats_kernel(
    const __hip_bfloat16* __restrict__ Pb,   // [8192][256], batch-local
    const int* __restrict__ knn, float* __restrict__ outFeat,
    float* __restrict__ psum, float* __restrict__ psq, int qq0, int prow) {
  const int c = threadIdx.x;
  float s = 0.f, s2 = 0.f;
  const int q0 = qq0 + blockIdx.x * 16;
  for (int q = 0; q < 16; ++q) {
    int qq = q0 + q;
    float qc = outFeat[(size_t)qq*256 + c];  // Q, staged here by matmulQ
    float m = -1e30f;
    const int* kn = knn + (size_t)qq * KNN;
#pragma unroll
    for (int k = 0; k < KNN; ++k) {
      int idx = kn[k];                       // batch-local point index
      float v = __bfloat162float(Pb[(size_t)idx*256 + c]) + qc;
      m = fmaxf(m, v);
      s += v;
      s2 = fmaf(v, v, s2);
    }
    outFeat[(size_t)qq*256 + c] = m;
  }
  psum[(size_t)(prow + blockIdx.x)*256 + c] = s;
  psq [(size_t)(prow + blockIdx.x)*256 + c] = s2;
}

__global__ __launch_bounds__(256) void reduce_stats_kernel(
    const float* __restrict__ psum, const float* __restrict__ psq,
    const float* __restrict__ gamma, const float* __restrict__ beta,
    float* __restrict__ ss) {
  const int c = blockIdx.x, t = threadIdx.x;
  float s  = psum[(size_t)t*256 + c] + psum[(size_t)(t+256)*256 + c];
  float s2 = psq [(size_t)t*256 + c] + psq [(size_t)(t+256)*256 + c];
#pragma unroll
  for (int off = 32; off >= 1; off >>= 1) {
    s  += __shfl_xor(s,  off);
    s2 += __shfl_xor(s2, off);
  }
  __shared__ float as[4], as2[4];
  const int lane = t & 63, wid = t >> 6;
  if (lane == 0) { as[wid] = s; as2[wid] = s2; }
  __syncthreads();
  if (t == 0) {
    float S  = (as[0]+as[1]) + (as[2]+as[3]);
    float S2 = (as2[0]+as2[1]) + (as2[2]+as2[3]);
    const float inv = 1.f / 163840.f;  // B*S*K
    float mean = S * inv;
    float var  = S2 * inv - mean * mean;
    float sc = rsqrtf(var + 1e-5f) * gamma[c];
    ss[c]       = sc;
    ss[256 + c] = beta[c] - mean * sc;
  }
}

__global__ __launch_bounds__(256) void finalize_kernel(
    float* __restrict__ f, const float* __restrict__ ss) {
  int e = blockIdx.x * 256 + threadIdx.x;
  float v = fmaf(f[e], ss[threadIdx.x], ss[256 + threadIdx.x]);
  f[e] = v > 0.f ? v : 0.f;
}

extern "C" void kernel_launch(void* const* d_in, const int* in_sizes, int n_in,
                              void* d_out, int out_size, void* d_ws, size_t ws_size,
                              hipStream_t stream) {
  const float* xyz      = (const float*)d_in[0];
  const float* feat     = (const float*)d_in[1];
  const float* conv_w   = (const float*)d_in[2];   // [262][256]
  const float* bn_gamma = (const float*)d_in[3];
  const float* bn_beta  = (const float*)d_in[4];
  const int*   far0     = (const int*)d_in[5];

  char* ws = (char*)d_ws;
  int*   sample_int = (int*)  (ws + 0);
  int*   knn        = (int*)  (ws + 32768);
  float* Wd         = (float*)(ws + 688128);
  float* psum       = (float*)(ws + 822272);
  float* psq        = (float*)(ws + 1346560);
  float* ss         = (float*)(ws + 1870848);
  __hip_bfloat16* Pb = (__hip_bfloat16*)(ws + 2097152);  // 4.19 MB, reused per batch

  float* out     = (float*)d_out;
  float* outFeat = out + 24576;                  // new_feat region [4][2048][256]

  fps_kernel  <<<dim3(4),    dim3(256),  0, stream>>>(xyz, far0, sample_int, out);
  knn_kernel  <<<dim3(2048), dim3(256),  0, stream>>>(xyz, sample_int, knn);
  wdiff_kernel<<<dim3(131),  dim3(256),  0, stream>>>(conv_w, Wd);

  // Q = center @ (W2-W1), f32, staged into d_out's new_feat region
  matmul131_kernel<false><<<dim3(256), dim3(128), 0, stream>>>(
      feat, xyz, sample_int, Wd, (void*)outFeat);

  // Per batch: P_b = feat_aug_b @ W1 (bf16), then maxh/stats for that batch
  for (int b = 0; b < 4; ++b) {
    matmul131_kernel<true><<<dim3(256), dim3(128), 0, stream>>>(
        feat + (size_t)b*NPTS*128, xyz + (size_t)b*NPTS*3,
        (const int*)nullptr, conv_w, (void*)Pb);
    stats_kernel<<<dim3(128), dim3(256), 0, stream>>>(
        Pb, knn + (size_t)b*NSAMP*KNN, outFeat + (size_t)b*NSAMP*256,
        psum, psq, 0, b*128);
  }

  reduce_stats_kernel<<<dim3(256), dim3(256), 0, stream>>>(psum, psq, bn_gamma, bn_beta, ss);
  finalize_kernel   <<<dim3(8192), dim3(256), 0, stream>>>(outFeat, ss);
}

// Round 7
// 2859.006 us; speedup vs baseline: 1.0625x; 1.0625x over previous
//
#include <hip/hip_runtime.h>
#include <hip/hip_bf16.h>

// B=4, N=8192, S=2048, C=128, c_in=131, c_out=256, K=20 (fixed by setup_inputs).
//
// Algebra: h = (knn_feat-center)@W1 + center@W2 = P[knn_idx] + Q.
// BN(gamma>0) and ReLU monotone => max_k commutes.
//
// ws layout (needs ~6.3 MB): see kernel_launch.

#define NPTS   8192
#define NSAMP  2048
#define KNN    20

typedef float v2f __attribute__((ext_vector_type(2)));
typedef unsigned long long u64;

// ---------- DPP reduction helpers (GCN/CDNA row ops, wave64) ----------
// full-wave: xor1(0xB1), xor2(0x4E), ror4(0x124), ror8(0x128) -> row-of-16
// reduced; bcast15(0x142, rm 0xa), bcast31(0x143, rm 0xc) -> lane 63 has wave
// result. Proven on HW (rounds 5-6).
template<int CTRL, int RM>
__device__ __forceinline__ u64 dpp_kmax(u64 k) {
  unsigned lo = (unsigned)k, hi = (unsigned)(k >> 32);
  unsigned lo2 = (unsigned)__builtin_amdgcn_update_dpp((int)lo, (int)lo, CTRL, RM, 0xf, false);
  unsigned hi2 = (unsigned)__builtin_amdgcn_update_dpp((int)hi, (int)hi, CTRL, RM, 0xf, false);
  u64 o = ((u64)hi2 << 32) | lo2;
  return o > k ? o : k;
}

template<int CTRL, int RM>
__device__ __forceinline__ u64 dpp_kmin(u64 k) {
  unsigned lo = (unsigned)k, hi = (unsigned)(k >> 32);
  unsigned lo2 = (unsigned)__builtin_amdgcn_update_dpp((int)lo, (int)lo, CTRL, RM, 0xf, false);
  unsigned hi2 = (unsigned)__builtin_amdgcn_update_dpp((int)hi, (int)hi, CTRL, RM, 0xf, false);
  u64 o = ((u64)hi2 << 32) | lo2;
  return o < k ? o : k;
}

__device__ __forceinline__ u64 umax64(u64 a, u64 b) { return a > b ? a : b; }

// FPS v6: 1024 thr (4 waves/SIMD, issue-bound regime per r5 counters), 8 pts/thr.
// Cuts per-wave instructions vs v4:
//  - u64 keys (dist_bits<<32 | ~idx) from the start: 7-max tree + 6 DPP stages,
//    no ballot/readlane/recovery rescan. dist>=0 => u64 order == (value, min idx)
//    == reference argmax tie-break, bit-exact.
//  - cross-wave combine via single LDS atomicMax (lane 63), 3-slot rotation
//    (zero slot (it+2)%3 now; atomics -> (it+1)%3; read after barrier). All
//    zero/atomic/read pairs separated by the one barrier => race-free.
//  - NO global stores in the loop (they forced vmcnt(0) drain at each barrier):
//    stage cur in LDS, bulk flush at the end.
//  - packed v2f update (v_pk_add/mul), contract(off); strict _rn semantics.
__global__ __launch_bounds__(1024, 1) void fps_kernel(
    const float* __restrict__ xyz, const int* __restrict__ farthest0,
    int* __restrict__ sample_int, float* __restrict__ out) {
  __shared__ float s_x[NPTS], s_y[NPTS], s_z[NPTS];   // 96 KiB
  __shared__ int   s_samp[NSAMP];                     // 8 KiB
  __shared__ u64   slot[3];
  const int b = blockIdx.x, tid = threadIdx.x;
  const int lane = tid & 63;
  const float* xb = xyz + (size_t)b * NPTS * 3;

  for (int p = tid; p < NPTS; p += 1024) {
    s_x[p] = xb[3*p]; s_y[p] = xb[3*p+1]; s_z[p] = xb[3*p+2];
  }
  if (tid < 3) slot[tid] = 0ull;
  __syncthreads();

  v2f px[4], py[4], pz[4], dist[4];
  unsigned notg[8];
#pragma unroll
  for (int j = 0; j < 4; ++j) {
    int p = tid*8 + 2*j;                     // contiguous ownership
    px[j] = v2f{s_x[p], s_x[p+1]};
    py[j] = v2f{s_y[p], s_y[p+1]};
    pz[j] = v2f{s_z[p], s_z[p+1]};
    dist[j] = v2f{1e10f, 1e10f};             // reference init 10000000000.0
  }
#pragma unroll
  for (int j = 0; j < 8; ++j) notg[j] = ~(unsigned)(tid*8 + j);

  int cur = farthest0[b];

  for (int it = 0; it < NSAMP; ++it) {
    if (tid == 0) s_samp[it] = cur;          // LDS only; scan emits carry
    if (it == NSAMP - 1) break;              // last winner never used further
    if (tid == 64) slot[(it+2)%3] = 0ull;    // future target; read/atomic of this
                                             // slot are across >=1 barrier away
    float cx = s_x[cur], cy = s_y[cur], cz = s_z[cur];   // uniform broadcast
    v2f cxx = {cx, cx}, cyy = {cy, cy}, czz = {cz, cz};
    {
#pragma clang fp contract(off)
#pragma unroll
      for (int j = 0; j < 4; ++j) {
        v2f dx = px[j] - cxx;
        v2f dy = py[j] - cyy;
        v2f dz = pz[j] - czz;
        v2f dd = (dx*dx + dy*dy) + dz*dz;    // ((x^2+y^2)+z^2), no fma
        dist[j].x = fminf(dist[j].x, dd.x);
        dist[j].y = fminf(dist[j].y, dd.y);
      }
    }
    // u64 keys: (dist_bits<<32) | ~global_idx ; dist>=0 so u64 max is exact
    u64 k0 = ((u64)__float_as_uint(dist[0].x) << 32) | notg[0];
    u64 k1 = ((u64)__float_as_uint(dist[0].y) << 32) | notg[1];
    u64 k2 = ((u64)__float_as_uint(dist[1].x) << 32) | notg[2];
    u64 k3 = ((u64)__float_as_uint(dist[1].y) << 32) | notg[3];
    u64 k4 = ((u64)__float_as_uint(dist[2].x) << 32) | notg[4];
    u64 k5 = ((u64)__float_as_uint(dist[2].y) << 32) | notg[5];
    u64 k6 = ((u64)__float_as_uint(dist[3].x) << 32) | notg[6];
    u64 k7 = ((u64)__float_as_uint(dist[3].y) << 32) | notg[7];
    u64 k = umax64(umax64(umax64(k0, k1), umax64(k2, k3)),
                   umax64(umax64(k4, k5), umax64(k6, k7)));
    // wave reduce to lane 63
    k = dpp_kmax<0xB1, 0xf>(k);
    k = dpp_kmax<0x4E, 0xf>(k);
    k = dpp_kmax<0x124, 0xf>(k);
    k = dpp_kmax<0x128, 0xf>(k);
    k = dpp_kmax<0x142, 0xa>(k);
    k = dpp_kmax<0x143, 0xc>(k);
    if (lane == 63) atomicMax(&slot[(it+1)%3], k);
    __syncthreads();                         // the ONLY barrier per iteration
    cur = (int)(~(unsigned)slot[(it+1)%3]);  // uniform LDS read
  }

  __syncthreads();
  // bulk flush: sample_int + outidx + outxyz (xyz regenerated from LDS)
  float* outxyz = out + (size_t)b * NSAMP * 3;
  float* outidx = out + 24576 + 2097152 + (size_t)b * NSAMP;
  for (int it = tid; it < NSAMP; it += 1024) {
    int idx = s_samp[it];
    sample_int[(b << 11) + it] = idx;
    outidx[it] = (float)idx;
    outxyz[3*it]   = s_x[idx];
    outxyz[3*it+1] = s_y[idx];
    outxyz[3*it+2] = s_z[idx];
  }
}

// kNN v3: 1 wave/query, two chunks of 4096 pts (64 regs/lane), masked argmin
// extraction with DPP u64 wave-min, exact merge of the two sorted top-20 lists.
__global__ __launch_bounds__(256) void knn_kernel(
    const float* __restrict__ xyz, const int* __restrict__ sample_int,
    int* __restrict__ knn_out) {
  __shared__ u64 lists[4][2][KNN];
  const int tid  = threadIdx.x;
  const int lane = tid & 63, w = tid >> 6;
  const int qq   = blockIdx.x * 4 + w;
  const int b    = qq >> 11;
  const float* xb = xyz + (size_t)b * NPTS * 3;
  const int sidx = sample_int[qq];
  const float sx = xb[3*sidx], sy = xb[3*sidx+1], sz = xb[3*sidx+2];
  const float sqs = __fadd_rn(__fadd_rn(__fmul_rn(sx,sx), __fmul_rn(sy,sy)), __fmul_rn(sz,sz));

  for (int ch = 0; ch < 2; ++ch) {
    const int pbase = ch * 4096;
    float d[64];
#pragma unroll
    for (int i = 0; i < 64; ++i) {
      int p = pbase + i*64 + lane;
      float x = xb[3*p], y = xb[3*p+1], z = xb[3*p+2];
      float dot = __fadd_rn(__fadd_rn(__fmul_rn(sx,x), __fmul_rn(sy,y)), __fmul_rn(sz,z));
      float sqx = __fadd_rn(__fadd_rn(__fmul_rn(x,x), __fmul_rn(y,y)), __fmul_rn(z,z));
      d[i] = __fadd_rn(__fsub_rn(sqs, __fmul_rn(2.0f, dot)), sqx);  // (||s||^2-2dot)+||x||^2
    }
    u64 msk = 0ull;
    for (int kk = 0; kk < KNN; ++kk) {
      float bv = 1e30f; int bs = 0;
#pragma unroll
      for (int i = 0; i < 64; ++i) {
        float dc = (msk & (1ull << i)) ? 1e30f : d[i];
        if (dc < bv) { bv = dc; bs = i; }   // strict <: smallest slot on ties
      }
      unsigned gi = (unsigned)(pbase + bs*64 + lane);
      u64 key = ((u64)__float_as_uint(bv) << 32) | gi;
      key = dpp_kmin<0xB1, 0xf>(key);
      key = dpp_kmin<0x4E, 0xf>(key);
      key = dpp_kmin<0x124, 0xf>(key);
      key = dpp_kmin<0x128, 0xf>(key);
      key = dpp_kmin<0x142, 0xa>(key);
      key = dpp_kmin<0x143, 0xc>(key);
      unsigned glo = (unsigned)__builtin_amdgcn_readlane((int)(unsigned)key, 63);
      unsigned ghi = (unsigned)__builtin_amdgcn_readlane((int)(unsigned)(key >> 32), 63);
      if (lane == (int)(glo & 63u)) msk |= 1ull << ((glo - pbase) >> 6);
      if (lane == 0) lists[w][ch][kk] = ((u64)ghi << 32) | glo;
    }
  }
  // merge the two ascending 20-lists by exact rank (keys distinct: idx unique)
  u64 mykey = ~0ull; int rank = 64;
  if (lane < 40) {
    int li = lane >= 20 ? 1 : 0;
    int e  = li ? lane - 20 : lane;
    mykey = lists[w][li][e];
    int cnt = e;
    const u64* oth = &lists[w][li ^ 1][0];
#pragma unroll
    for (int j = 0; j < KNN; ++j) cnt += (oth[j] < mykey) ? 1 : 0;
    rank = cnt;
  }
  if (rank < KNN) knn_out[(size_t)qq * KNN + rank] = (int)(mykey & 0xFFFFFFFFull);
}

__global__ void wdiff_kernel(const float* __restrict__ W, float* __restrict__ Wd) {
  int i = blockIdx.x * 256 + threadIdx.x;      // 131 blocks * 256 = 33536 exactly
  Wd[i] = W[131*256 + i] - W[i];
}

// OUT[row, c] = sum_{k<131} A(row)[k] * W[k*256+c]
template<bool BF16OUT>
__global__ __launch_bounds__(128) void matmul131_kernel(
    const float* __restrict__ featb, const float* __restrict__ xyzb,
    const int* __restrict__ gidx,
    const float* __restrict__ W, void* __restrict__ outp) {
  __shared__ float tile[32][132];
  const int tid = threadIdx.x;
  const int r0  = blockIdx.x << 5;
  for (int i = tid; i < 32*131; i += 128) {
    int r = i / 131;
    int k = i - r*131;
    int row = r0 + r;
    int src;
    if (gidx) { int bb = row >> 11; src = (bb << 13) + gidx[row]; }
    else      { src = row; }
    float v = (k < 128) ? featb[(size_t)src*128 + k]
                        : xyzb[(size_t)src*3 + (k-128)];
    tile[r][k] = v;
  }
  __syncthreads();
  float acc0[32], acc1[32];
#pragma unroll
  for (int r = 0; r < 32; ++r) { acc0[r] = 0.f; acc1[r] = 0.f; }
  const int c0 = tid, c1 = tid + 128;
  for (int k = 0; k < 128; k += 4) {
    float w00 = W[(k+0)*256+c0], w01 = W[(k+1)*256+c0], w02 = W[(k+2)*256+c0], w03 = W[(k+3)*256+c0];
    float w10 = W[(k+0)*256+c1], w11 = W[(k+1)*256+c1], w12 = W[(k+2)*256+c1], w13 = W[(k+3)*256+c1];
#pragma unroll
    for (int r = 0; r < 32; ++r) {
      float4 a = *(const float4*)&tile[r][k];
      acc0[r] = fmaf(a.x, w00, acc0[r]); acc0[r] = fmaf(a.y, w01, acc0[r]);
      acc0[r] = fmaf(a.z, w02, acc0[r]); acc0[r] = fmaf(a.w, w03, acc0[r]);
      acc1[r] = fmaf(a.x, w10, acc1[r]); acc1[r] = fmaf(a.y, w11, acc1[r]);
      acc1[r] = fmaf(a.z, w12, acc1[r]); acc1[r] = fmaf(a.w, w13, acc1[r]);
    }
  }
#pragma unroll
  for (int kk = 128; kk < 131; ++kk) {
    float w0 = W[kk*256+c0], w1 = W[kk*256+c1];
#pragma unroll
    for (int r = 0; r < 32; ++r) {
      float a = tile[r][kk];
      acc0[r] = fmaf(a, w0, acc0[r]);
      acc1[r] = fmaf(a, w1, acc1[r]);
    }
  }
#pragma unroll
  for (int r = 0; r < 32; ++r) {
    if (BF16OUT) {
      __hip_bfloat16* o = (__hip_bfloat16*)outp;
      o[(size_t)(r0+r)*256 + c0] = __float2bfloat16(acc0[r]);
      o[(size_t)(r0+r)*256 + c1] = __float2bfloat16(acc1[r]);
    } else {
      float* o = (float*)outp;
      o[(size_t)(r0+r)*256 + c0] = acc0[r];
      o[(size_t)(r0+r)*256 + c1] = acc1[r];
    }
  }
}

// One batch per launch. Qb == outFeat: each (qq,c) element is read (qc) exactly
// once by the thread that later overwrites it with maxh.
__global__ __launch_bounds__(256) void stats_kernel(
    const __hip_bfloat16* __restrict__ Pb,   // [8192][256], batch-local
    const int* __restrict__ knn, float* __restrict__ outFeat,
    float* __restrict__ psum, float* __restrict__ psq, int qq0, int prow) {
  const int c = threadIdx.x;
  float s = 0.f, s2 = 0.f;
  const int q0 = qq0 + blockIdx.x * 16;
  for (int q = 0; q < 16; ++q) {
    int qq = q0 + q;
    float qc = outFeat[(size_t)qq*256 + c];  // Q, staged here by matmulQ
    float m = -1e30f;
    const int* kn = knn + (size_t)qq * KNN;
#pragma unroll
    for (int k = 0; k < KNN; ++k) {
      int idx = kn[k];                       // batch-local point index
      float v = __bfloat162float(Pb[(size_t)idx*256 + c]) + qc;
      m = fmaxf(m, v);
      s += v;
      s2 = fmaf(v, v, s2);
    }
    outFeat[(size_t)qq*256 + c] = m;
  }
  psum[(size_t)(prow + blockIdx.x)*256 + c] = s;
  psq [(size_t)(prow + blockIdx.x)*256 + c] = s2;
}

__global__ __launch_bounds__(256) void reduce_stats_kernel(
    const float* __restrict__ psum, const float* __restrict__ psq,
    const float* __restrict__ gamma, const float* __restrict__ beta,
    float* __restrict__ ss) {
  const int c = blockIdx.x, t = threadIdx.x;
  float s  = psum[(size_t)t*256 + c] + psum[(size_t)(t+256)*256 + c];
  float s2 = psq [(size_t)t*256 + c] + psq [(size_t)(t+256)*256 + c];
#pragma unroll
  for (int off = 32; off >= 1; off >>= 1) {
    s  += __shfl_xor(s,  off);
    s2 += __shfl_xor(s2, off);
  }
  __shared__ float as[4], as2[4];
  const int lane = t & 63, wid = t >> 6;
  if (lane == 0) { as[wid] = s; as2[wid] = s2; }
  __syncthreads();
  if (t == 0) {
    float S  = (as[0]+as[1]) + (as[2]+as[3]);
    float S2 = (as2[0]+as2[1]) + (as2[2]+as2[3]);
    const float inv = 1.f / 163840.f;  // B*S*K
    float mean = S * inv;
    float var  = S2 * inv - mean * mean;
    float sc = rsqrtf(var + 1e-5f) * gamma[c];
    ss[c]       = sc;
    ss[256 + c] = beta[c] - mean * sc;
  }
}

__global__ __launch_bounds__(256) void finalize_kernel(
    float* __restrict__ f, const float* __restrict__ ss) {
  int e = blockIdx.x * 256 + threadIdx.x;
  float v = fmaf(f[e], ss[threadIdx.x], ss[256 + threadIdx.x]);
  f[e] = v > 0.f ? v : 0.f;
}

extern "C" void kernel_launch(void* const* d_in, const int* in_sizes, int n_in,
                              void* d_out, int out_size, void* d_ws, size_t ws_size,
                              hipStream_t stream) {
  const float* xyz      = (const float*)d_in[0];
  const float* feat     = (const float*)d_in[1];
  const float* conv_w   = (const float*)d_in[2];   // [262][256]
  const float* bn_gamma = (const float*)d_in[3];
  const float* bn_beta  = (const float*)d_in[4];
  const int*   far0     = (const int*)d_in[5];

  char* ws = (char*)d_ws;
  int*   sample_int = (int*)  (ws + 0);
  int*   knn        = (int*)  (ws + 32768);
  float* Wd         = (float*)(ws + 688128);
  float* psum       = (float*)(ws + 822272);
  float* psq        = (float*)(ws + 1346560);
  float* ss         = (float*)(ws + 1870848);
  __hip_bfloat16* Pb = (__hip_bfloat16*)(ws + 2097152);  // 4.19 MB, reused per batch

  float* out     = (float*)d_out;
  float* outFeat = out + 24576;                  // new_feat region [4][2048][256]

  fps_kernel  <<<dim3(4),    dim3(1024), 0, stream>>>(xyz, far0, sample_int, out);
  knn_kernel  <<<dim3(2048), dim3(256),  0, stream>>>(xyz, sample_int, knn);
  wdiff_kernel<<<dim3(131),  dim3(256),  0, stream>>>(conv_w, Wd);

  // Q = center @ (W2-W1), f32, staged into d_out's new_feat region
  matmul131_kernel<false><<<dim3(256), dim3(128), 0, stream>>>(
      feat, xyz, sample_int, Wd, (void*)outFeat);

  // Per batch: P_b = feat_aug_b @ W1 (bf16), then maxh/stats for that batch
  for (int b = 0; b < 4; ++b) {
    matmul131_kernel<true><<<dim3(256), dim3(128), 0, stream>>>(
        feat + (size_t)b*NPTS*128, xyz + (size_t)b*NPTS*3,
        (const int*)nullptr, conv_w, (void*)Pb);
    stats_kernel<<<dim3(128), dim3(256), 0, stream>>>(
        Pb, knn + (size_t)b*NSAMP*KNN, outFeat + (size_t)b*NSAMP*256,
        psum, psq, 0, b*128);
  }

  reduce_stats_kernel<<<dim3(256), dim3(256), 0, stream>>>(psum, psq, bn_gamma, bn_beta, ss);
  finalize_kernel   <<<dim3(8192), dim3(256), 0, stream>>>(outFeat, ss);
}

// Round 8
// 2114.368 us; speedup vs baseline: 1.4367x; 1.3522x over previous
//
#include <hip/hip_runtime.h>
#include <hip/hip_bf16.h>

// B=4, N=8192, S=2048, C=128, c_in=131, c_out=256, K=20 (fixed by setup_inputs).
//
// Algebra: h = (knn_feat-center)@W1 + center@W2 = P[knn_idx] + Q.
// BN(gamma>0) and ReLU monotone => max_k commutes.

#define NPTS   8192
#define NSAMP  2048
#define KNN    20

typedef unsigned long long u64;
typedef unsigned int u32;
typedef unsigned short u16;

// ---------- DPP reduction helpers (wave64; validated on HW rounds 5-7) ----------
// xor1(0xB1), xor2(0x4E), ror4(0x124), ror8(0x128) -> row-of-16 reduced;
// bcast15(0x142, rm 0xa), bcast31(0x143, rm 0xc) -> lane 63 holds wave result.
template<int CTRL, int RM>
__device__ __forceinline__ u64 dpp_kmax(u64 k) {
  unsigned lo = (unsigned)k, hi = (unsigned)(k >> 32);
  unsigned lo2 = (unsigned)__builtin_amdgcn_update_dpp((int)lo, (int)lo, CTRL, RM, 0xf, false);
  unsigned hi2 = (unsigned)__builtin_amdgcn_update_dpp((int)hi, (int)hi, CTRL, RM, 0xf, false);
  u64 o = ((u64)hi2 << 32) | lo2;
  return o > k ? o : k;
}
template<int CTRL, int RM>
__device__ __forceinline__ u64 dpp_kmin(u64 k) {
  unsigned lo = (unsigned)k, hi = (unsigned)(k >> 32);
  unsigned lo2 = (unsigned)__builtin_amdgcn_update_dpp((int)lo, (int)lo, CTRL, RM, 0xf, false);
  unsigned hi2 = (unsigned)__builtin_amdgcn_update_dpp((int)hi, (int)hi, CTRL, RM, 0xf, false);
  u64 o = ((u64)hi2 << 32) | lo2;
  return o < k ? o : k;
}
__device__ __forceinline__ u64 umax64(u64 a, u64 b) { return a > b ? a : b; }

__device__ __forceinline__ unsigned mspread4(unsigned q) {  // 4b -> every 3rd bit
  return (q & 1u) | ((q & 2u) << 2) | ((q & 4u) << 4) | ((q & 8u) << 6);
}

// FPS v7: Morton counting-sort into per-lane buckets of 8 pts; per-lane bbox +
// cached max-key enables exact skip (bound >= ub => no element of the bucket
// can change => cached key stays exact). Winner's lane has gap 0 => never
// skipped. Keys (dist_bits<<32 | ~orig_idx): global max == reference argmax
// with first-index tie-break, independent of the (nondeterministic) scatter
// permutation => outputs deterministic and bit-exact.
__global__ __launch_bounds__(1024, 1) void fps_kernel(
    const float* __restrict__ xyz, const int* __restrict__ farthest0,
    int* __restrict__ sample_int, float* __restrict__ out) {
  __shared__ float sxs[NPTS], sys[NPTS], szs[NPTS];   // sorted coords, 96 KB
  __shared__ u16   spos[NPTS];                        // orig -> sorted pos, 16 KB
  __shared__ u16   sidxr[NPTS];                       // sorted -> orig, 16 KB
  __shared__ int   s_samp[NSAMP];                     // 8 KB
  __shared__ u32   hist[4096];                        // 16 KB
  __shared__ u32   part[1024];                        // 4 KB
  __shared__ u64   slot[3];
  const int b = blockIdx.x, tid = threadIdx.x, lane = tid & 63;
  const float* xb = xyz + (size_t)b * NPTS * 3;

  // ---- counting sort by 12-bit Morton (4 bits/axis, range [-5.2, 5.2]) ----
  for (int i = tid; i < 4096; i += 1024) hist[i] = 0u;
  if (tid < 3) slot[tid] = 0ull;
  __syncthreads();

  float ox[8], oy[8], oz[8];
  int cell[8];
#pragma unroll
  for (int j = 0; j < 8; ++j) {
    int p = tid * 8 + j;
    float x = xb[3*p], y = xb[3*p+1], z = xb[3*p+2];
    ox[j] = x; oy[j] = y; oz[j] = z;
    unsigned qx = (unsigned)(int)fminf(fmaxf((x + 5.2f) * 1.5384615f, 0.f), 15.f);
    unsigned qy = (unsigned)(int)fminf(fmaxf((y + 5.2f) * 1.5384615f, 0.f), 15.f);
    unsigned qz = (unsigned)(int)fminf(fmaxf((z + 5.2f) * 1.5384615f, 0.f), 15.f);
    cell[j] = (int)(mspread4(qx) | (mspread4(qy) << 1) | (mspread4(qz) << 2));
    atomicAdd(&hist[cell[j]], 1u);
  }
  __syncthreads();

  // exclusive prefix sum over hist[4096]: thread t owns hist[4t..4t+3]
  u32 h0 = hist[4*tid], h1 = hist[4*tid+1], h2 = hist[4*tid+2], h3 = hist[4*tid+3];
  u32 mysum = h0 + h1 + h2 + h3;
  part[tid] = mysum;
  __syncthreads();
  for (int off = 1; off < 1024; off <<= 1) {
    u32 u = (tid >= off) ? part[tid - off] : 0u;
    u32 v = part[tid];
    __syncthreads();
    part[tid] = u + v;
    __syncthreads();
  }
  u32 base = part[tid] - mysum;
  hist[4*tid]   = base;
  hist[4*tid+1] = base + h0;
  hist[4*tid+2] = base + h0 + h1;
  hist[4*tid+3] = base + h0 + h1 + h2;
  __syncthreads();

#pragma unroll
  for (int j = 0; j < 8; ++j) {
    u32 p = atomicAdd(&hist[cell[j]], 1u);
    sxs[p] = ox[j]; sys[p] = oy[j]; szs[p] = oz[j];
    sidxr[p] = (u16)(tid * 8 + j);
    spos[tid * 8 + j] = (u16)p;
  }
  __syncthreads();

  // ---- per-lane bucket: 8 sorted-consecutive points ----
  float px[8], py[8], pz[8], dist[8];
  unsigned notg[8];
#pragma unroll
  for (int j = 0; j < 8; ++j) {
    int p = tid * 8 + j;
    px[j] = sxs[p]; py[j] = sys[p]; pz[j] = szs[p];
    notg[j] = ~(unsigned)sidxr[p];
    dist[j] = 1e10f;                       // reference init 10000000000.0
  }
  float bxmin = px[0], bxmax = px[0], bymin = py[0], bymax = py[0], bzmin = pz[0], bzmax = pz[0];
#pragma unroll
  for (int j = 1; j < 8; ++j) {
    bxmin = fminf(bxmin, px[j]); bxmax = fmaxf(bxmax, px[j]);
    bymin = fminf(bymin, py[j]); bymax = fmaxf(bymax, py[j]);
    bzmin = fminf(bzmin, pz[j]); bzmax = fmaxf(bzmax, pz[j]);
  }
  u64 klane = ((u64)__float_as_uint(1e10f) << 32);   // ub=1e10 -> live at it=0
  u64 kw    = 0ull;
  int cur = farthest0[b];

  for (int it = 0; it < NSAMP; ++it) {
    if (tid == 0) s_samp[it] = cur;        // scan emits carry (index before update)
    if (it == NSAMP - 1) break;
    if (tid == 64) slot[(it+2)%3] = 0ull;  // rotation proven race-free (v6)
    int sp = spos[cur];                    // uniform chain: spos -> coords
    float cx = sxs[sp], cy = sys[sp], cz = szs[sp];

    // per-lane exact skip test: bound*(1-1e-6) >= ub  =>  no dist in bucket changes
    float gx = fmaxf(fmaxf(__fsub_rn(bxmin, cx), __fsub_rn(cx, bxmax)), 0.f);
    float gy = fmaxf(fmaxf(__fsub_rn(bymin, cy), __fsub_rn(cy, bymax)), 0.f);
    float gz = fmaxf(fmaxf(__fsub_rn(bzmin, cz), __fsub_rn(cz, bzmax)), 0.f);
    float bound = __fadd_rn(__fadd_rn(__fmul_rn(gx,gx), __fmul_rn(gy,gy)), __fmul_rn(gz,gz));
    float ub = __uint_as_float((unsigned)(klane >> 32));
    bool live = !(__fmul_rn(bound, 0.999999f) >= ub);

    if (__any(live)) {
      if (live) {
        // strict IEEE update, no FMA contraction (matches reference bit-exact)
#pragma unroll
        for (int j = 0; j < 8; ++j) {
          float dx = __fsub_rn(px[j], cx);
          float dy = __fsub_rn(py[j], cy);
          float dz = __fsub_rn(pz[j], cz);
          float d  = __fadd_rn(__fadd_rn(__fmul_rn(dx,dx), __fmul_rn(dy,dy)), __fmul_rn(dz,dz));
          dist[j] = fminf(dist[j], d);
        }
        u64 k0 = ((u64)__float_as_uint(dist[0]) << 32) | notg[0];
        u64 k1 = ((u64)__float_as_uint(dist[1]) << 32) | notg[1];
        u64 k2 = ((u64)__float_as_uint(dist[2]) << 32) | notg[2];
        u64 k3 = ((u64)__float_as_uint(dist[3]) << 32) | notg[3];
        u64 k4 = ((u64)__float_as_uint(dist[4]) << 32) | notg[4];
        u64 k5 = ((u64)__float_as_uint(dist[5]) << 32) | notg[5];
        u64 k6 = ((u64)__float_as_uint(dist[6]) << 32) | notg[6];
        u64 k7 = ((u64)__float_as_uint(dist[7]) << 32) | notg[7];
        klane = umax64(umax64(umax64(k0,k1), umax64(k2,k3)),
                       umax64(umax64(k4,k5), umax64(k6,k7)));
      }
      // wave max over (valid cached or fresh) per-lane keys; exec = all lanes here
      u64 k = klane;
      k = dpp_kmax<0xB1, 0xf>(k);
      k = dpp_kmax<0x4E, 0xf>(k);
      k = dpp_kmax<0x124, 0xf>(k);
      k = dpp_kmax<0x128, 0xf>(k);
      k = dpp_kmax<0x142, 0xa>(k);
      k = dpp_kmax<0x143, 0xc>(k);
      unsigned klo = (unsigned)__builtin_amdgcn_readlane((int)(unsigned)k, 63);
      unsigned khi = (unsigned)__builtin_amdgcn_readlane((int)(unsigned)(k >> 32), 63);
      kw = ((u64)khi << 32) | klo;
    }
    if (lane == 0) atomicMax(&slot[(it+1)%3], kw);
    __syncthreads();                       // the ONLY barrier per iteration
    cur = (int)(~(unsigned)slot[(it+1)%3]);
  }

  __syncthreads();
  float* outxyz = out + (size_t)b * NSAMP * 3;
  float* outidx = out + 24576 + 2097152 + (size_t)b * NSAMP;
  for (int it = tid; it < NSAMP; it += 1024) {
    int o = s_samp[it];
    int sp = spos[o];
    sample_int[(b << 11) + it] = o;
    outidx[it] = (float)o;
    outxyz[3*it]   = sxs[sp];
    outxyz[3*it+1] = sys[sp];
    outxyz[3*it+2] = szs[sp];
  }
}

// kNN v3 (unchanged): 1 wave/query, two chunks of 4096 pts, masked argmin with
// DPP u64 wave-min, exact merge of the two sorted top-20 lists.
__global__ __launch_bounds__(256) void knn_kernel(
    const float* __restrict__ xyz, const int* __restrict__ sample_int,
    int* __restrict__ knn_out) {
  __shared__ u64 lists[4][2][KNN];
  const int tid  = threadIdx.x;
  const int lane = tid & 63, w = tid >> 6;
  const int qq   = blockIdx.x * 4 + w;
  const int b    = qq >> 11;
  const float* xb = xyz + (size_t)b * NPTS * 3;
  const int sidx = sample_int[qq];
  const float sx = xb[3*sidx], sy = xb[3*sidx+1], sz = xb[3*sidx+2];
  const float sqs = __fadd_rn(__fadd_rn(__fmul_rn(sx,sx), __fmul_rn(sy,sy)), __fmul_rn(sz,sz));

  for (int ch = 0; ch < 2; ++ch) {
    const int pbase = ch * 4096;
    float d[64];
#pragma unroll
    for (int i = 0; i < 64; ++i) {
      int p = pbase + i*64 + lane;
      float x = xb[3*p], y = xb[3*p+1], z = xb[3*p+2];
      float dot = __fadd_rn(__fadd_rn(__fmul_rn(sx,x), __fmul_rn(sy,y)), __fmul_rn(sz,z));
      float sqx = __fadd_rn(__fadd_rn(__fmul_rn(x,x), __fmul_rn(y,y)), __fmul_rn(z,z));
      d[i] = __fadd_rn(__fsub_rn(sqs, __fmul_rn(2.0f, dot)), sqx);  // (||s||^2-2dot)+||x||^2
    }
    u64 msk = 0ull;
    for (int kk = 0; kk < KNN; ++kk) {
      float bv = 1e30f; int bs = 0;
#pragma unroll
      for (int i = 0; i < 64; ++i) {
        float dc = (msk & (1ull << i)) ? 1e30f : d[i];
        if (dc < bv) { bv = dc; bs = i; }   // strict <: smallest slot on ties
      }
      unsigned gi = (unsigned)(pbase + bs*64 + lane);
      u64 key = ((u64)__float_as_uint(bv) << 32) | gi;
      key = dpp_kmin<0xB1, 0xf>(key);
      key = dpp_kmin<0x4E, 0xf>(key);
      key = dpp_kmin<0x124, 0xf>(key);
      key = dpp_kmin<0x128, 0xf>(key);
      key = dpp_kmin<0x142, 0xa>(key);
      key = dpp_kmin<0x143, 0xc>(key);
      unsigned glo = (unsigned)__builtin_amdgcn_readlane((int)(unsigned)key, 63);
      unsigned ghi = (unsigned)__builtin_amdgcn_readlane((int)(unsigned)(key >> 32), 63);
      if (lane == (int)(glo & 63u)) msk |= 1ull << ((glo - pbase) >> 6);
      if (lane == 0) lists[w][ch][kk] = ((u64)ghi << 32) | glo;
    }
  }
  u64 mykey = ~0ull; int rank = 64;
  if (lane < 40) {
    int li = lane >= 20 ? 1 : 0;
    int e  = li ? lane - 20 : lane;
    mykey = lists[w][li][e];
    int cnt = e;
    const u64* oth = &lists[w][li ^ 1][0];
#pragma unroll
    for (int j = 0; j < KNN; ++j) cnt += (oth[j] < mykey) ? 1 : 0;
    rank = cnt;
  }
  if (rank < KNN) knn_out[(size_t)qq * KNN + rank] = (int)(mykey & 0xFFFFFFFFull);
}

__global__ void wdiff_kernel(const float* __restrict__ W, float* __restrict__ Wd) {
  int i = blockIdx.x * 256 + threadIdx.x;      // 131 blocks * 256 = 33536 exactly
  Wd[i] = W[131*256 + i] - W[i];
}

// OUT[row, c] = sum_{k<131} A(row)[k] * W[k*256+c]
template<bool BF16OUT>
__global__ __launch_bounds__(128) void matmul131_kernel(
    const float* __restrict__ featb, const float* __restrict__ xyzb,
    const int* __restrict__ gidx,
    const float* __restrict__ W, void* __restrict__ outp) {
  __shared__ float tile[32][132];
  const int tid = threadIdx.x;
  const int r0  = blockIdx.x << 5;
  for (int i = tid; i < 32*131; i += 128) {
    int r = i / 131;
    int k = i - r*131;
    int row = r0 + r;
    int src;
    if (gidx) { int bb = row >> 11; src = (bb << 13) + gidx[row]; }
    else      { src = row; }
    float v = (k < 128) ? featb[(size_t)src*128 + k]
                        : xyzb[(size_t)src*3 + (k-128)];
    tile[r][k] = v;
  }
  __syncthreads();
  float acc0[32], acc1[32];
#pragma unroll
  for (int r = 0; r < 32; ++r) { acc0[r] = 0.f; acc1[r] = 0.f; }
  const int c0 = tid, c1 = tid + 128;
  for (int k = 0; k < 128; k += 4) {
    float w00 = W[(k+0)*256+c0], w01 = W[(k+1)*256+c0], w02 = W[(k+2)*256+c0], w03 = W[(k+3)*256+c0];
    float w10 = W[(k+0)*256+c1], w11 = W[(k+1)*256+c1], w12 = W[(k+2)*256+c1], w13 = W[(k+3)*256+c1];
#pragma unroll
    for (int r = 0; r < 32; ++r) {
      float4 a = *(const float4*)&tile[r][k];
      acc0[r] = fmaf(a.x, w00, acc0[r]); acc0[r] = fmaf(a.y, w01, acc0[r]);
      acc0[r] = fmaf(a.z, w02, acc0[r]); acc0[r] = fmaf(a.w, w03, acc0[r]);
      acc1[r] = fmaf(a.x, w10, acc1[r]); acc1[r] = fmaf(a.y, w11, acc1[r]);
      acc1[r] = fmaf(a.z, w12, acc1[r]); acc1[r] = fmaf(a.w, w13, acc1[r]);
    }
  }
#pragma unroll
  for (int kk = 128; kk < 131; ++kk) {
    float w0 = W[kk*256+c0], w1 = W[kk*256+c1];
#pragma unroll
    for (int r = 0; r < 32; ++r) {
      float a = tile[r][kk];
      acc0[r] = fmaf(a, w0, acc0[r]);
      acc1[r] = fmaf(a, w1, acc1[r]);
    }
  }
#pragma unroll
  for (int r = 0; r < 32; ++r) {
    if (BF16OUT) {
      __hip_bfloat16* o = (__hip_bfloat16*)outp;
      o[(size_t)(r0+r)*256 + c0] = __float2bfloat16(acc0[r]);
      o[(size_t)(r0+r)*256 + c1] = __float2bfloat16(acc1[r]);
    } else {
      float* o = (float*)outp;
      o[(size_t)(r0+r)*256 + c0] = acc0[r];
      o[(size_t)(r0+r)*256 + c1] = acc1[r];
    }
  }
}

// One batch per launch. Qb == outFeat: each (qq,c) element is read (qc) exactly
// once by the thread that later overwrites it with maxh.
__global__ __launch_bounds__(256) void stats_kernel(
    const __hip_bfloat16* __restrict__ Pb,   // [8192][256], batch-local
    const int* __restrict__ knn, float* __restrict__ outFeat,
    float* __restrict__ psum, float* __restrict__ psq, int qq0, int prow) {
  const int c = threadIdx.x;
  float s = 0.f, s2 = 0.f;
  const int q0 = qq0 + blockIdx.x * 16;
  for (int q = 0; q < 16; ++q) {
    int qq = q0 + q;
    float qc = outFeat[(size_t)qq*256 + c];  // Q, staged here by matmulQ
    float m = -1e30f;
    const int* kn = knn + (size_t)qq * KNN;
#pragma unroll
    for (int k = 0; k < KNN; ++k) {
      int idx = kn[k];                       // batch-local point index
      float v = __bfloat162float(Pb[(size_t)idx*256 + c]) + qc;
      m = fmaxf(m, v);
      s += v;
      s2 = fmaf(v, v, s2);
    }
    outFeat[(size_t)qq*256 + c] = m;
  }
  psum[(size_t)(prow + blockIdx.x)*256 + c] = s;
  psq [(size_t)(prow + blockIdx.x)*256 + c] = s2;
}

__global__ __launch_bounds__(256) void reduce_stats_kernel(
    const float* __restrict__ psum, const float* __restrict__ psq,
    const float* __restrict__ gamma, const float* __restrict__ beta,
    float* __restrict__ ss) {
  const int c = blockIdx.x, t = threadIdx.x;
  float s  = psum[(size_t)t*256 + c] + psum[(size_t)(t+256)*256 + c];
  float s2 = psq [(size_t)t*256 + c] + psq [(size_t)(t+256)*256 + c];
#pragma unroll
  for (int off = 32; off >= 1; off >>= 1) {
    s  += __shfl_xor(s,  off);
    s2 += __shfl_xor(s2, off);
  }
  __shared__ float as[4], as2[4];
  const int lane = t & 63, wid = t >> 6;
  if (lane == 0) { as[wid] = s; as2[wid] = s2; }
  __syncthreads();
  if (t == 0) {
    float S  = (as[0]+as[1]) + (as[2]+as[3]);
    float S2 = (as2[0]+as2[1]) + (as2[2]+as2[3]);
    const float inv = 1.f / 163840.f;  // B*S*K
    float mean = S * inv;
    float var  = S2 * inv - mean * mean;
    float sc = rsqrtf(var + 1e-5f) * gamma[c];
    ss[c]       = sc;
    ss[256 + c] = beta[c] - mean * sc;
  }
}

__global__ __launch_bounds__(256) void finalize_kernel(
    float* __restrict__ f, const float* __restrict__ ss) {
  int e = blockIdx.x * 256 + threadIdx.x;
  float v = fmaf(f[e], ss[threadIdx.x], ss[256 + threadIdx.x]);
  f[e] = v > 0.f ? v : 0.f;
}

extern "C" void kernel_launch(void* const* d_in, const int* in_sizes, int n_in,
                              void* d_out, int out_size, void* d_ws, size_t ws_size,
                              hipStream_t stream) {
  const float* xyz      = (const float*)d_in[0];
  const float* feat     = (const float*)d_in[1];
  const float* conv_w   = (const float*)d_in[2];   // [262][256]
  const float* bn_gamma = (const float*)d_in[3];
  const float* bn_beta  = (const float*)d_in[4];
  const int*   far0     = (const int*)d_in[5];

  char* ws = (char*)d_ws;
  int*   sample_int = (int*)  (ws + 0);
  int*   knn        = (int*)  (ws + 32768);
  float* Wd         = (float*)(ws + 688128);
  float* psum       = (float*)(ws + 822272);
  float* psq        = (float*)(ws + 1346560);
  float* ss         = (float*)(ws + 1870848);
  __hip_bfloat16* Pb = (__hip_bfloat16*)(ws + 2097152);  // 4.19 MB, reused per batch

  float* out     = (float*)d_out;
  float* outFeat = out + 24576;                  // new_feat region [4][2048][256]

  fps_kernel  <<<dim3(4),    dim3(1024), 0, stream>>>(xyz, far0, sample_int, out);
  knn_kernel  <<<dim3(2048), dim3(256),  0, stream>>>(xyz, sample_int, knn);
  wdiff_kernel<<<dim3(131),  dim3(256),  0, stream>>>(conv_w, Wd);

  // Q = center @ (W2-W1), f32, staged into d_out's new_feat region
  matmul131_kernel<false><<<dim3(256), dim3(128), 0, stream>>>(
      feat, xyz, sample_int, Wd, (void*)outFeat);

  // Per batch: P_b = feat_aug_b @ W1 (bf16), then maxh/stats for that batch
  for (int b = 0; b < 4; ++b) {
    matmul131_kernel<true><<<dim3(256), dim3(128), 0, stream>>>(
        feat + (size_t)b*NPTS*128, xyz + (size_t)b*NPTS*3,
        (const int*)nullptr, conv_w, (void*)Pb);
    stats_kernel<<<dim3(128), dim3(256), 0, stream>>>(
        Pb, knn + (size_t)b*NSAMP*KNN, outFeat + (size_t)b*NSAMP*256,
        psum, psq, 0, b*128);
  }

  reduce_stats_kernel<<<dim3(256), dim3(256), 0, stream>>>(psum, psq, bn_gamma, bn_beta, ss);
  finalize_kernel   <<<dim3(8192), dim3(256), 0, stream>>>(outFeat, ss);
}